// Round 1
// baseline (1101.469 us; speedup 1.0000x reference)
//
#include <hip/hip_runtime.h>
#include <hip/hip_bf16.h>

#define NB   524288   // nodes (B)
#define NC   256      // clusters (C)
#define ND   128      // feature dim (D)

typedef __attribute__((ext_vector_type(4))) float f32x4;
typedef __attribute__((ext_vector_type(8))) short bf16x8;

// ---------- fast math helpers (v_exp_f32 / v_rcp_f32 based) ----------
__device__ inline float fast_exp(float x)  { return exp2f(x * 1.4426950408889634f); }
__device__ inline float fast_sigmoid(float x) { return __builtin_amdgcn_rcpf(1.f + fast_exp(-x)); }
__device__ inline float fast_tanh(float x) { return 1.f - 2.f * __builtin_amdgcn_rcpf(1.f + fast_exp(2.f * x)); }

__device__ inline unsigned short f2bf(float f) {
    unsigned u = __float_as_uint(f);
    u += 0x7FFFu + ((u >> 16) & 1u);   // round-to-nearest-even
    return (unsigned short)(u >> 16);
}

__device__ inline bf16x8 pack8(const float* __restrict__ p) {
    float4 a = *(const float4*)p;
    float4 b = *(const float4*)(p + 4);
    bf16x8 r;
    r[0] = (short)f2bf(a.x); r[1] = (short)f2bf(a.y);
    r[2] = (short)f2bf(a.z); r[3] = (short)f2bf(a.w);
    r[4] = (short)f2bf(b.x); r[5] = (short)f2bf(b.y);
    r[6] = (short)f2bf(b.z); r[7] = (short)f2bf(b.w);
    return r;
}

// order-preserving float->uint encoding for atomicMax
__device__ inline unsigned enc_f32(float s) {
    unsigned b = __float_as_uint(s);
    return b ^ (unsigned)(((int)b >> 31) | (int)0x80000000);
}

// ---------------- K1: per-cluster precompute ----------------
// g_trans = tanh(g @ Fs_w.T + Fs_b); gG1 = g_trans @ G1_w.T + G1_b; qb = g @ Wq.T + attn_bias
__global__ __launch_bounds__(128) void k1_cluster_prep(
    const float* __restrict__ g, const float* __restrict__ Wq,
    const float* __restrict__ attn_bias,
    const float* __restrict__ Fs_w, const float* __restrict__ Fs_b,
    const float* __restrict__ G1_w, const float* __restrict__ G1_b,
    float* __restrict__ g_trans, float* __restrict__ gG1, float* __restrict__ qb) {
    const int c = blockIdx.x, d = threadIdx.x;
    __shared__ float g_lds[ND];
    __shared__ float gt_lds[ND];
    g_lds[d] = g[c * ND + d];
    __syncthreads();
    float accF = Fs_b[d], accQ = attn_bias[d];
    const float* fr = Fs_w + d * ND;
    const float* qr = Wq + d * ND;
    for (int k = 0; k < ND; ++k) {
        float gv = g_lds[k];
        accF += fr[k] * gv;
        accQ += qr[k] * gv;
    }
    float gt = fast_tanh(accF);
    g_trans[c * ND + d] = gt;
    gt_lds[d] = gt;
    qb[c * ND + d] = accQ;
    __syncthreads();
    float accG = G1_b[d];
    const float* gr = G1_w + d * ND;
    for (int k = 0; k < ND; ++k) accG += gr[k] * gt_lds[k];
    gG1[c * ND + d] = accG;
}

// ---------------- K2: pass 1 (dominant) ----------------
// Per 16-node tile: k = h@Wk.T and hH1 = h@H1_w.T via mfma_f32_16x16x32_bf16,
// then epilogue: score (shfl-reduced) and h_merged write.
__global__ __launch_bounds__(256) void k2_pass1(
    const float* __restrict__ h, const int* __restrict__ cid,
    const float* __restrict__ Wk, const float* __restrict__ H1w,
    const float* __restrict__ H1b, const float* __restrict__ Wsw,
    const float* __restrict__ Wsb, const float* __restrict__ g_trans,
    const float* __restrict__ gG1, const float* __restrict__ qb,
    float* __restrict__ outh, float* __restrict__ score) {
    __shared__ float k_lds[16][132];    // +4 pad: 2-way (free) bank aliasing
    __shared__ float h1_lds[16][132];
    const int tid = threadIdx.x;
    const int w = tid >> 6, l = tid & 63;
    const int l15 = l & 15, lg = l >> 4;

    // Weight B-fragments in registers. Wave w owns dim-tiles {w, w+4}.
    // B-frag for tile t, kchunk c: lane l holds W[t*16+(l&15)][c*32+(l>>4)*8 + 0..7]
    bf16x8 bk[2][4], bh[2][4];
#pragma unroll
    for (int t2 = 0; t2 < 2; ++t2) {
        const int trow = (w + t2 * 4) * 16 + l15;
#pragma unroll
        for (int c = 0; c < 4; ++c) {
            const int col = c * 32 + lg * 8;
            bk[t2][c] = pack8(Wk + trow * ND + col);
            bh[t2][c] = pack8(H1w + trow * ND + col);
        }
    }
    const float Wsb0 = Wsb[0];
    const int nb0 = blockIdx.x * 256;   // 256 nodes per block, 16 tiles of 16

    for (int it = 0; it < 16; ++it) {
        const int nb = nb0 + it * 16;
        // A-fragments straight from global: lane l row (l&15), cols c*32+(l>>4)*8
        bf16x8 af[4];
        const float* hrow = h + (size_t)(nb + l15) * ND + lg * 8;
#pragma unroll
        for (int c = 0; c < 4; ++c) af[c] = pack8(hrow + c * 32);

        f32x4 acck0 = {0.f, 0.f, 0.f, 0.f}, acck1 = {0.f, 0.f, 0.f, 0.f};
        f32x4 acch0 = {0.f, 0.f, 0.f, 0.f}, acch1 = {0.f, 0.f, 0.f, 0.f};
#pragma unroll
        for (int c = 0; c < 4; ++c) {
            acck0 = __builtin_amdgcn_mfma_f32_16x16x32_bf16(af[c], bk[0][c], acck0, 0, 0, 0);
            acck1 = __builtin_amdgcn_mfma_f32_16x16x32_bf16(af[c], bk[1][c], acck1, 0, 0, 0);
            acch0 = __builtin_amdgcn_mfma_f32_16x16x32_bf16(af[c], bh[0][c], acch0, 0, 0, 0);
            acch1 = __builtin_amdgcn_mfma_f32_16x16x32_bf16(af[c], bh[1][c], acch1, 0, 0, 0);
        }
        // C/D layout: col = lane&15 (dim within tile), row = (lane>>4)*4 + reg (node)
        {
            const int d0 = w * 16 + l15, d1 = (w + 4) * 16 + l15;
#pragma unroll
            for (int r = 0; r < 4; ++r) {
                const int nrow = lg * 4 + r;
                k_lds[nrow][d0] = acck0[r];
                k_lds[nrow][d1] = acck1[r];
                h1_lds[nrow][d0] = acch0[r];
                h1_lds[nrow][d1] = acch1[r];
            }
        }
        __syncthreads();
        // Epilogue: wave w handles nodes 4w..4w+3; lane l handles dims 2l,2l+1
#pragma unroll
        for (int ni = 0; ni < 4; ++ni) {
            const int n = w * 4 + ni;
            const int node = nb + n;
            const int cc = cid[node];
            float2 kv  = *(const float2*)&k_lds[n][2 * l];
            float2 h1v = *(const float2*)&h1_lds[n][2 * l];
            float2 qv  = *(const float2*)(qb + cc * ND + 2 * l);
            float2 ggv = *(const float2*)(gG1 + cc * ND + 2 * l);
            float2 gtv = *(const float2*)(g_trans + cc * ND + 2 * l);
            float2 hv  = *(const float2*)(h + (size_t)node * ND + 2 * l);
            float2 hbv = *(const float2*)(H1b + 2 * l);
            float2 wsv = *(const float2*)(Wsw + 2 * l);
            // score partial: tanh(k + qb) . Ws
            float sp = fast_tanh(kv.x + qv.x) * wsv.x + fast_tanh(kv.y + qv.y) * wsv.y;
#pragma unroll
            for (int off = 32; off; off >>= 1) sp += __shfl_xor(sp, off, 64);
            if (l == 0) score[node] = sp + Wsb0;
            // gate: z1 = sigmoid(hH1 + H1_b + gG1[cid]); out = (1-z1)*h + z1*g_trans[cid]
            float z0 = fast_sigmoid(h1v.x + hbv.x + ggv.x);
            float z1 = fast_sigmoid(h1v.y + hbv.y + ggv.y);
            float2 o = {(1.f - z0) * hv.x + z0 * gtv.x,
                        (1.f - z1) * hv.y + z1 * gtv.y};
            *(float2*)(outh + (size_t)node * ND + 2 * l) = o;
        }
        __syncthreads();
    }
}

// ---------------- K3: segment max of score ----------------
__global__ __launch_bounds__(256) void k3_segmax(
    const float* __restrict__ score, const int* __restrict__ cid,
    unsigned* __restrict__ m_enc) {
    __shared__ unsigned mloc[NC];
    const int t = threadIdx.x;
    mloc[t] = 0u;
    __syncthreads();
    for (int i = blockIdx.x * 256 + t; i < NB; i += 256 * 256) {
        atomicMax(&mloc[cid[i]], enc_f32(score[i]));
    }
    __syncthreads();
    atomicMax(m_enc + t, mloc[t]);
}

// ---------------- K4: pass 2 — weighted segment sum ----------------
// Each block owns HALF the dims (64) for 2048 nodes; LDS accumulator 256x64.
__global__ __launch_bounds__(256) void k4_pass2(
    const float* __restrict__ h, const int* __restrict__ cid,
    const float* __restrict__ score, const unsigned* __restrict__ m_enc,
    float* __restrict__ ctx_raw, float* __restrict__ denom) {
    __shared__ float cloc[NC * 64];
    __shared__ float dloc[NC];
    __shared__ float mloc[NC];
    const int t = threadIdx.x, w = t >> 6, l = t & 63;
    const int half = blockIdx.x & 1, bg = blockIdx.x >> 1;
    for (int i = t; i < NC * 64; i += 256) cloc[i] = 0.f;
    dloc[t] = 0.f;
    {   // decode per-cluster max (memset-0 encodes "empty" -> non-finite -> 0)
        unsigned u = m_enc[t];
        unsigned bits = (u & 0x80000000u) ? (u ^ 0x80000000u) : ~u;
        float f = __uint_as_float(bits);
        mloc[t] = ((bits & 0x7F800000u) == 0x7F800000u) ? 0.f : f;
    }
    __syncthreads();
    const int n0 = bg * 2048 + w * 512;
    const float* hcol = h + half * 64 + l;
    for (int nn = 0; nn < 512; nn += 4) {
        const int n = n0 + nn;
        float4 sc = *(const float4*)(score + n);     // broadcast loads
        int4 c4 = *(const int4*)(cid + n);
        float e0 = fast_exp(sc.x - mloc[c4.x]);
        float e1 = fast_exp(sc.y - mloc[c4.y]);
        float e2 = fast_exp(sc.z - mloc[c4.z]);
        float e3 = fast_exp(sc.w - mloc[c4.w]);
        float h0 = hcol[(size_t)n * ND];
        float h1 = hcol[(size_t)(n + 1) * ND];
        float h2 = hcol[(size_t)(n + 2) * ND];
        float h3 = hcol[(size_t)(n + 3) * ND];
        atomicAdd(&cloc[c4.x * 64 + l], e0 * h0);
        atomicAdd(&cloc[c4.y * 64 + l], e1 * h1);
        atomicAdd(&cloc[c4.z * 64 + l], e2 * h2);
        atomicAdd(&cloc[c4.w * 64 + l], e3 * h3);
        if (l == 0 && half == 0) {
            atomicAdd(&dloc[c4.x], e0);
            atomicAdd(&dloc[c4.y], e1);
            atomicAdd(&dloc[c4.z], e2);
            atomicAdd(&dloc[c4.w], e3);
        }
    }
    __syncthreads();
    for (int i = t; i < NC * 64; i += 256) {
        const int c = i >> 6;
        unsafeAtomicAdd(&ctx_raw[c * ND + half * 64 + (i & 63)], cloc[i]);
    }
    if (half == 0) unsafeAtomicAdd(&denom[t], dloc[t]);
}

// ---------------- K5: finalize virtual nodes ----------------
__global__ __launch_bounds__(128) void k5_final(
    const float* __restrict__ g, const float* __restrict__ ctx_raw,
    const float* __restrict__ denom,
    const float* __restrict__ W_w, const float* __restrict__ W_b,
    const float* __restrict__ H2_w, const float* __restrict__ H2_b,
    const float* __restrict__ G2_w, const float* __restrict__ G2_b,
    float* __restrict__ out_g) {
    const int c = blockIdx.x, d = threadIdx.x;
    __shared__ float ctx_l[ND], ht_l[ND], g_l[ND];
    float den = fmaxf(denom[c], 1e-20f);
    float ctxv = ctx_raw[c * ND + d] / den;
    ctx_l[d] = ctxv;
    g_l[d] = g[c * ND + d];
    __syncthreads();
    float acc = W_b[d];
    const float* wr = W_w + d * ND;
    for (int k = 0; k < ND; ++k) acc += wr[k] * ctx_l[k];
    float ht = fast_tanh(acc);
    ht_l[d] = ht;
    __syncthreads();
    float acc2 = H2_b[d] + G2_b[d];
    const float* h2r = H2_w + d * ND;
    const float* g2r = G2_w + d * ND;
    for (int k = 0; k < ND; ++k) acc2 += h2r[k] * g_l[k] + g2r[k] * ht_l[k];
    float z = fast_sigmoid(acc2);
    out_g[c * ND + d] = (1.f - z) * g_l[d] + z * ht;
}

extern "C" void kernel_launch(void* const* d_in, const int* in_sizes, int n_in,
                              void* d_out, int out_size, void* d_ws, size_t ws_size,
                              hipStream_t stream) {
    const float* h        = (const float*)d_in[0];
    const float* g        = (const float*)d_in[1];
    const int*   cid      = (const int*)d_in[2];
    const float* Wq       = (const float*)d_in[3];
    const float* Wk       = (const float*)d_in[4];
    const float* attnb    = (const float*)d_in[5];
    const float* Ws_w     = (const float*)d_in[6];
    const float* Ws_b     = (const float*)d_in[7];
    const float* W_w      = (const float*)d_in[8];
    const float* W_b      = (const float*)d_in[9];
    const float* Fs_w     = (const float*)d_in[10];
    const float* Fs_b     = (const float*)d_in[11];
    const float* H1_w     = (const float*)d_in[12];
    const float* H1_b     = (const float*)d_in[13];
    const float* G1_w     = (const float*)d_in[14];
    const float* G1_b     = (const float*)d_in[15];
    const float* H2_w     = (const float*)d_in[16];
    const float* H2_b     = (const float*)d_in[17];
    const float* G2_w     = (const float*)d_in[18];
    const float* G2_b     = (const float*)d_in[19];
    float* out = (float*)d_out;
    float* ws  = (float*)d_ws;

    // ws layout (floats)
    float*    g_trans = ws;               // 32768
    float*    gG1     = ws + 32768;       // 32768
    float*    qb      = ws + 65536;       // 32768
    float*    score   = ws + 98304;       // 524288
    unsigned* m_enc   = (unsigned*)(ws + 622592); // 256
    float*    denom   = ws + 622848;      // 256
    float*    ctx_raw = ws + 623104;      // 32768
    // zero the atomic-accumulated regions (m_enc, denom, ctx_raw are contiguous)
    hipMemsetAsync(ws + 622592, 0, (256 + 256 + 32768) * sizeof(float), stream);

    k1_cluster_prep<<<NC, ND, 0, stream>>>(g, Wq, attnb, Fs_w, Fs_b, G1_w, G1_b,
                                           g_trans, gG1, qb);
    k2_pass1<<<2048, 256, 0, stream>>>(h, cid, Wk, H1_w, H1_b, Ws_w, Ws_b,
                                       g_trans, gG1, qb, out, score);
    k3_segmax<<<256, 256, 0, stream>>>(score, cid, m_enc);
    k4_pass2<<<512, 256, 0, stream>>>(h, cid, score, m_enc, ctx_raw, denom);
    k5_final<<<NC, ND, 0, stream>>>(g, ctx_raw, denom, W_w, W_b,
                                    H2_w, H2_b, G2_w, G2_b,
                                    out + (size_t)NB * ND);
}

// Round 3
// 1081.603 us; speedup vs baseline: 1.0184x; 1.0184x over previous
//
#include <hip/hip_runtime.h>
#include <hip/hip_bf16.h>

#define NB   524288   // nodes (B)
#define NC   256      // clusters (C)
#define ND   128      // feature dim (D)

typedef __attribute__((ext_vector_type(4))) float f32x4;
typedef __attribute__((ext_vector_type(8))) short bf16x8;

// ---------- fast math helpers ----------
__device__ inline float fast_exp(float x)  { return exp2f(x * 1.4426950408889634f); }
__device__ inline float fast_sigmoid(float x) { return __builtin_amdgcn_rcpf(1.f + fast_exp(-x)); }
__device__ inline float fast_tanh(float x) { return 1.f - 2.f * __builtin_amdgcn_rcpf(1.f + fast_exp(2.f * x)); }

__device__ inline unsigned short f2bf(float f) {
    unsigned u = __float_as_uint(f);
    u += 0x7FFFu + ((u >> 16) & 1u);   // round-to-nearest-even
    return (unsigned short)(u >> 16);
}

__device__ inline bf16x8 pack8(const float* __restrict__ p) {
    float4 a = *(const float4*)p;
    float4 b = *(const float4*)(p + 4);
    bf16x8 r;
    r[0] = (short)f2bf(a.x); r[1] = (short)f2bf(a.y);
    r[2] = (short)f2bf(a.z); r[3] = (short)f2bf(a.w);
    r[4] = (short)f2bf(b.x); r[5] = (short)f2bf(b.y);
    r[6] = (short)f2bf(b.z); r[7] = (short)f2bf(b.w);
    return r;
}

// order-preserving float->uint encoding for atomicMax
__device__ inline unsigned enc_f32(float s) {
    unsigned b = __float_as_uint(s);
    return b ^ (unsigned)(((int)b >> 31) | (int)0x80000000);
}

// ---------------- K1: per-cluster precompute ----------------
__global__ __launch_bounds__(128) void k1_cluster_prep(
    const float* __restrict__ g, const float* __restrict__ Wq,
    const float* __restrict__ attn_bias,
    const float* __restrict__ Fs_w, const float* __restrict__ Fs_b,
    const float* __restrict__ G1_w, const float* __restrict__ G1_b,
    float* __restrict__ g_trans, float* __restrict__ gG1, float* __restrict__ qb) {
    const int c = blockIdx.x, d = threadIdx.x;
    __shared__ float g_lds[ND];
    __shared__ float gt_lds[ND];
    g_lds[d] = g[c * ND + d];
    __syncthreads();
    float accF = Fs_b[d], accQ = attn_bias[d];
    const float* fr = Fs_w + d * ND;
    const float* qr = Wq + d * ND;
    for (int k = 0; k < ND; ++k) {
        float gv = g_lds[k];
        accF += fr[k] * gv;
        accQ += qr[k] * gv;
    }
    float gt = fast_tanh(accF);
    g_trans[c * ND + d] = gt;
    gt_lds[d] = gt;
    qb[c * ND + d] = accQ;
    __syncthreads();
    float accG = G1_b[d];
    const float* gr = G1_w + d * ND;
    for (int k = 0; k < ND; ++k) accG += gr[k] * gt_lds[k];
    gG1[c * ND + d] = accG;
}

// ---------------- K2: pass 1 — barrier-free, no LDS ----------------
// BLOCK owns 256 nodes (16 tiles of 16). ALL 4 waves process EVERY tile;
// wave w covers dim-tiles {w, w+4} (dims [16w,16w+16) and [64+16w,+16)),
// so across the 4 waves every (node, dim) is written exactly once.
// k = h@Wk.T and hH1 = h@H1_w.T via mfma_f32_16x16x32_bf16; gate epilogue in
// MFMA register layout; per-wave 32-dim score partial reduced via 4x shfl_xor
// and accumulated with one global f32 atomic per node per wave (4 total).
// Ws_b dropped: constant shift cancels in segment softmax.
__global__ __launch_bounds__(256) void k2_pass1(
    const float* __restrict__ h, const int* __restrict__ cid,
    const float* __restrict__ Wk, const float* __restrict__ H1w,
    const float* __restrict__ H1b, const float* __restrict__ Wsw,
    const float* __restrict__ g_trans, const float* __restrict__ gG1,
    const float* __restrict__ qb,
    float* __restrict__ outh, float* __restrict__ score) {
    const int tid = threadIdx.x;
    const int w = tid >> 6, l = tid & 63;
    const int l15 = l & 15, lg = l >> 4;

    // Weight B-fragments in registers (loaded once). Wave w owns dim-tiles {w, w+4}.
    bf16x8 bk[2][4], bh[2][4];
#pragma unroll
    for (int t2 = 0; t2 < 2; ++t2) {
        const int trow = (w + t2 * 4) * 16 + l15;
#pragma unroll
        for (int c = 0; c < 4; ++c) {
            const int col = c * 32 + lg * 8;
            bk[t2][c] = pack8(Wk + trow * ND + col);
            bh[t2][c] = pack8(H1w + trow * ND + col);
        }
    }
    const int d0 = w * 16 + l15, d1 = d0 + 64;
    const float ws0 = Wsw[d0], ws1 = Wsw[d1];
    const float hb0 = H1b[d0], hb1 = H1b[d1];

    const int nb0 = blockIdx.x * 256;   // block's 256 nodes, 16 tiles of 16

    for (int it = 0; it < 16; ++it) {
        const int nb = nb0 + it * 16;
        // A-fragments straight from global: lane row (l&15), cols c*32+(l>>4)*8
        bf16x8 af[4];
        const float* hrow = h + (size_t)(nb + l15) * ND + lg * 8;
#pragma unroll
        for (int c = 0; c < 4; ++c) af[c] = pack8(hrow + c * 32);

        f32x4 acck0 = {0.f, 0.f, 0.f, 0.f}, acck1 = {0.f, 0.f, 0.f, 0.f};
        f32x4 acch0 = {0.f, 0.f, 0.f, 0.f}, acch1 = {0.f, 0.f, 0.f, 0.f};
#pragma unroll
        for (int c = 0; c < 4; ++c) {
            acck0 = __builtin_amdgcn_mfma_f32_16x16x32_bf16(af[c], bk[0][c], acck0, 0, 0, 0);
            acck1 = __builtin_amdgcn_mfma_f32_16x16x32_bf16(af[c], bk[1][c], acck1, 0, 0, 0);
            acch0 = __builtin_amdgcn_mfma_f32_16x16x32_bf16(af[c], bh[0][c], acch0, 0, 0, 0);
            acch1 = __builtin_amdgcn_mfma_f32_16x16x32_bf16(af[c], bh[1][c], acch1, 0, 0, 0);
        }
        // C/D layout: col = lane&15 (dim in tile), row = (lane>>4)*4 + reg (node)
#pragma unroll
        for (int r = 0; r < 4; ++r) {
            const int node = nb + lg * 4 + r;
            const int cc = cid[node];
            const float* qrow = qb + cc * ND;
            const float* grow = gG1 + cc * ND;
            const float* trow = g_trans + cc * ND;
            const float* hrw  = h + (size_t)node * ND;
            float q0  = qrow[d0], q1  = qrow[d1];
            float gg0 = grow[d0], gg1 = grow[d1];
            float gt0 = trow[d0], gt1 = trow[d1];
            float hv0 = hrw[d0],  hv1 = hrw[d1];
            // score partial over this wave's 32 dims
            float sp = fast_tanh(acck0[r] + q0) * ws0 + fast_tanh(acck1[r] + q1) * ws1;
            sp += __shfl_xor(sp, 1);
            sp += __shfl_xor(sp, 2);
            sp += __shfl_xor(sp, 4);
            sp += __shfl_xor(sp, 8);
            if (l15 == 0) unsafeAtomicAdd(&score[node], sp);
            // gate
            float z0 = fast_sigmoid(acch0[r] + hb0 + gg0);
            float z1 = fast_sigmoid(acch1[r] + hb1 + gg1);
            outh[(size_t)node * ND + d0] = (1.f - z0) * hv0 + z0 * gt0;
            outh[(size_t)node * ND + d1] = (1.f - z1) * hv1 + z1 * gt1;
        }
    }
}

// ---------------- K3: segment max of score ----------------
__global__ __launch_bounds__(256) void k3_segmax(
    const float* __restrict__ score, const int* __restrict__ cid,
    unsigned* __restrict__ m_enc) {
    __shared__ unsigned mloc[NC];
    const int t = threadIdx.x;
    mloc[t] = 0u;
    __syncthreads();
    for (int i = blockIdx.x * 256 + t; i < NB; i += 256 * 256) {
        atomicMax(&mloc[cid[i]], enc_f32(score[i]));
    }
    __syncthreads();
    atomicMax(m_enc + t, mloc[t]);
}

// ---------------- K4: pass 2 — weighted segment sum ----------------
// Each block owns a QUARTER of the dims (32) for 2048 nodes.
// LDS accumulator 256 x 33 (pad kills bank conflicts) = 33.8 KB -> 4 blocks/CU.
__global__ __launch_bounds__(256) void k4_pass2(
    const float* __restrict__ h, const int* __restrict__ cid,
    const float* __restrict__ score, const unsigned* __restrict__ m_enc,
    float* __restrict__ ctx_raw, float* __restrict__ denom) {
    __shared__ float cloc[NC * 33];
    __shared__ float dloc[NC];
    __shared__ float mloc[NC];
    const int t = threadIdx.x, w = t >> 6, l = t & 63;
    const int q = blockIdx.x & 3;        // dim quarter
    const int bg = blockIdx.x >> 2;      // node group (2048 nodes)
    for (int i = t; i < NC * 33; i += 256) cloc[i] = 0.f;
    dloc[t] = 0.f;
    {   // decode per-cluster max (memset-0 encodes "empty" -> non-finite -> 0)
        unsigned u = m_enc[t];
        unsigned bits = (u & 0x80000000u) ? (u ^ 0x80000000u) : ~u;
        float f = __uint_as_float(bits);
        mloc[t] = ((bits & 0x7F800000u) == 0x7F800000u) ? 0.f : f;
    }
    __syncthreads();
    const int colbase = q * 32 + (l & 7) * 4;   // 4 consecutive dims per lane
    const int n0 = bg * 2048 + w * 512;
    for (int nn = 0; nn < 512; nn += 8) {
        const int node = n0 + nn + (l >> 3);    // 8 nodes per wave-instruction
        float s = score[node];
        int c = cid[node];
        float e = fast_exp(s - mloc[c]);
        float4 hv = *(const float4*)(h + (size_t)node * ND + colbase);
        const int base = c * 33 + (l & 7) * 4;
        atomicAdd(&cloc[base + 0], e * hv.x);
        atomicAdd(&cloc[base + 1], e * hv.y);
        atomicAdd(&cloc[base + 2], e * hv.z);
        atomicAdd(&cloc[base + 3], e * hv.w);
        if ((l & 7) == 0 && q == 0) atomicAdd(&dloc[c], e);
    }
    __syncthreads();
    for (int i = t; i < NC * 32; i += 256) {
        const int c = i >> 5, col = i & 31;
        unsafeAtomicAdd(&ctx_raw[c * ND + q * 32 + col], cloc[c * 33 + col]);
    }
    if (q == 0) unsafeAtomicAdd(&denom[t], dloc[t]);
}

// ---------------- K5: finalize virtual nodes ----------------
__global__ __launch_bounds__(128) void k5_final(
    const float* __restrict__ g, const float* __restrict__ ctx_raw,
    const float* __restrict__ denom,
    const float* __restrict__ W_w, const float* __restrict__ W_b,
    const float* __restrict__ H2_w, const float* __restrict__ H2_b,
    const float* __restrict__ G2_w, const float* __restrict__ G2_b,
    float* __restrict__ out_g) {
    const int c = blockIdx.x, d = threadIdx.x;
    __shared__ float ctx_l[ND], ht_l[ND], g_l[ND];
    float den = fmaxf(denom[c], 1e-20f);
    float ctxv = ctx_raw[c * ND + d] / den;
    ctx_l[d] = ctxv;
    g_l[d] = g[c * ND + d];
    __syncthreads();
    float acc = W_b[d];
    const float* wr = W_w + d * ND;
    for (int k = 0; k < ND; ++k) acc += wr[k] * ctx_l[k];
    float ht = fast_tanh(acc);
    ht_l[d] = ht;
    __syncthreads();
    float acc2 = H2_b[d] + G2_b[d];
    const float* h2r = H2_w + d * ND;
    const float* g2r = G2_w + d * ND;
    for (int k = 0; k < ND; ++k) acc2 += h2r[k] * g_l[k] + g2r[k] * ht_l[k];
    float z = fast_sigmoid(acc2);
    out_g[c * ND + d] = (1.f - z) * g_l[d] + z * ht;
}

extern "C" void kernel_launch(void* const* d_in, const int* in_sizes, int n_in,
                              void* d_out, int out_size, void* d_ws, size_t ws_size,
                              hipStream_t stream) {
    const float* h     = (const float*)d_in[0];
    const float* g     = (const float*)d_in[1];
    const int*   cid   = (const int*)d_in[2];
    const float* Wq    = (const float*)d_in[3];
    const float* Wk    = (const float*)d_in[4];
    const float* attnb = (const float*)d_in[5];
    const float* Ws_w  = (const float*)d_in[6];
    const float* W_w   = (const float*)d_in[8];
    const float* W_b   = (const float*)d_in[9];
    const float* Fs_w  = (const float*)d_in[10];
    const float* Fs_b  = (const float*)d_in[11];
    const float* H1_w  = (const float*)d_in[12];
    const float* H1_b  = (const float*)d_in[13];
    const float* G1_w  = (const float*)d_in[14];
    const float* G1_b  = (const float*)d_in[15];
    const float* H2_w  = (const float*)d_in[16];
    const float* H2_b  = (const float*)d_in[17];
    const float* G2_w  = (const float*)d_in[18];
    const float* G2_b  = (const float*)d_in[19];
    float* out = (float*)d_out;
    float* ws  = (float*)d_ws;

    // ws layout (floats)
    float*    g_trans = ws;               // 32768
    float*    gG1     = ws + 32768;       // 32768
    float*    qb      = ws + 65536;       // 32768
    float*    score   = ws + 98304;       // 524288 (atomic-accumulated: must be 0)
    unsigned* m_enc   = (unsigned*)(ws + 622592); // 256
    float*    denom   = ws + 622848;      // 256
    float*    ctx_raw = ws + 623104;      // 32768
    // zero all atomic-accumulated regions (score..ctx_raw contiguous)
    hipMemsetAsync(ws + 98304, 0, (524288 + 256 + 256 + 32768) * sizeof(float), stream);

    k1_cluster_prep<<<NC, ND, 0, stream>>>(g, Wq, attnb, Fs_w, Fs_b, G1_w, G1_b,
                                           g_trans, gG1, qb);
    k2_pass1<<<2048, 256, 0, stream>>>(h, cid, Wk, H1_w, H1_b, Ws_w,
                                       g_trans, gG1, qb, out, score);
    k3_segmax<<<256, 256, 0, stream>>>(score, cid, m_enc);
    k4_pass2<<<1024, 256, 0, stream>>>(h, cid, score, m_enc, ctx_raw, denom);
    k5_final<<<NC, ND, 0, stream>>>(g, ctx_raw, denom, W_w, W_b,
                                    H2_w, H2_b, G2_w, G2_b,
                                    out + (size_t)NB * ND);
}